// Round 7
// baseline (376.482 us; speedup 1.0000x reference)
//
#include <hip/hip_runtime.h>

#define N_TOK  1024
#define D_DIM  1024
#define M_FFN  4096

typedef float f32x4 __attribute__((ext_vector_type(4)));

__device__ __forceinline__ float wave_reduce(float v) {
    #pragma unroll
    for (int off = 32; off > 0; off >>= 1) v += __shfl_xor(v, off);
    return v;
}

// ---- C(32 x N) = LN(A)(32 x K=1024) @ W(N x K)^T, LN folded exactly -----
// dot(LN(a),w) = rs*D - mean*rs*SG + SB with D=sum a*gw, SG=sum gw, SB=sum b*w.
// Inner loop keeps the R5 4-FMA/j core (gw4 replaces w4). Row stats computed
// in-block from L2-resident A (32 rows x 1024). mode 0: slab store,
// mode 1: +bias +silu.
__device__ __forceinline__ void gemm_fln_body(const float* __restrict__ A,
                                              const float* __restrict__ W,
                                              float* __restrict__ C,
                                              const float* __restrict__ bias,
                                              const float* __restrict__ ln_g,
                                              const float* __restrict__ ln_b,
                                              int N, int K, int kchunk, int mode,
                                              int bx, int by) {
    __shared__ float s_mean[32], s_rs[32];
    int t = threadIdx.x;
    int lane = t & 63, wid = t >> 6;

    // ---- per-row LN stats: wave wid covers rows wid*8 .. +7 (K fixed 1024)
    #pragma unroll
    for (int r = 0; r < 8; r++) {
        int row = wid * 8 + r;
        const float4* xp = (const float4*)(A + (size_t)row * 1024);
        float s = 0.f, q = 0.f;
        #pragma unroll
        for (int c = 0; c < 4; c++) {
            float4 x = xp[lane + c * 64];
            s += x.x + x.y + x.z + x.w;
            q += x.x*x.x + x.y*x.y + x.z*x.z + x.w*x.w;
        }
        s = wave_reduce(s); q = wave_reduce(q);
        if (lane == 0) {
            float mean = s * (1.f / 1024.f);
            float var  = q * (1.f / 1024.f) - mean * mean;
            s_mean[row] = mean;
            s_rs[row]   = rsqrtf(var + 1e-5f);
        }
    }
    __syncthreads();

    int ksub = lane & 15, nsub = lane >> 4;
    int mhalf = wid & 1, ngrp = wid >> 1;
    int n = bx * 8 + ngrp * 4 + nsub;
    int k0 = by * kchunk + ksub * 4;
    const float* wp = W + (size_t)n * K + k0;
    const float* ap = A + (size_t)(mhalf * 16) * K + k0;
    const float* gp = ln_g + k0;
    const float* bp = ln_b + k0;
    float D[16];
    #pragma unroll
    for (int j = 0; j < 16; j++) D[j] = 0.f;
    float SG = 0.f, SB = 0.f;
    for (int kk = 0; kk < kchunk; kk += 64) {
        f32x4 w4 = __builtin_nontemporal_load((const f32x4*)(wp + kk));
        float4 g4 = *(const float4*)(gp + kk);
        float4 b4 = *(const float4*)(bp + kk);
        float gwx = g4.x * w4.x, gwy = g4.y * w4.y,
              gwz = g4.z * w4.z, gww = g4.w * w4.w;
        SG += gwx + gwy + gwz + gww;
        SB += b4.x*w4.x + b4.y*w4.y + b4.z*w4.z + b4.w*w4.w;
        #pragma unroll
        for (int j = 0; j < 16; j++) {
            float4 a4 = *(const float4*)(ap + (size_t)j * K + kk);
            D[j] += a4.x*gwx + a4.y*gwy + a4.z*gwz + a4.w*gww;
        }
    }
    // reduce across the 16 ksub lanes
    #pragma unroll
    for (int j = 0; j < 16; j++) {
        #pragma unroll
        for (int off = 1; off < 16; off <<= 1)
            D[j] += __shfl_xor(D[j], off);
    }
    #pragma unroll
    for (int off = 1; off < 16; off <<= 1) {
        SG += __shfl_xor(SG, off);
        SB += __shfl_xor(SB, off);
    }
    if (ksub == 0) {
        int mbase = mhalf * 16;
        if (mode == 1) {
            float bn = bias[n];
            #pragma unroll
            for (int j = 0; j < 16; j++) {
                float mean = s_mean[mbase + j], rs = s_rs[mbase + j];
                float z = rs * D[j] - mean * rs * SG + SB + bn;
                C[(size_t)(mbase + j) * N + n] = z / (1.f + __expf(-z));
            }
        } else {
            #pragma unroll
            for (int j = 0; j < 16; j++) {
                float mean = s_mean[mbase + j], rs = s_rs[mbase + j];
                C[(size_t)(mbase + j) * N + n] = rs * D[j] - mean * rs * SG + SB;
            }
        }
    }
}

// ---- plain GEMM body (no LN), used by ffn2 -------------------------------
__device__ __forceinline__ void gemm_body(const float* __restrict__ A,
                                          const float* __restrict__ W,
                                          float* __restrict__ C,
                                          int N, int K, int kchunk,
                                          int bx, int by) {
    int t = threadIdx.x;
    int lane = t & 63, wid = t >> 6;
    int ksub = lane & 15, nsub = lane >> 4;
    int mhalf = wid & 1, ngrp = wid >> 1;
    int n = bx * 8 + ngrp * 4 + nsub;
    int k0 = by * kchunk + ksub * 4;
    const float* wp = W + (size_t)n * K + k0;
    const float* ap = A + (size_t)mhalf * 16 * K + k0;
    float acc[16];
    #pragma unroll
    for (int j = 0; j < 16; j++) acc[j] = 0.f;
    for (int kk = 0; kk < kchunk; kk += 64) {
        f32x4 w4 = __builtin_nontemporal_load((const f32x4*)(wp + kk));
        #pragma unroll
        for (int j = 0; j < 16; j++) {
            float4 a4 = *(const float4*)(ap + (size_t)j * K + kk);
            acc[j] += a4.x*w4.x + a4.y*w4.y + a4.z*w4.z + a4.w*w4.w;
        }
    }
    #pragma unroll
    for (int j = 0; j < 16; j++) {
        #pragma unroll
        for (int off = 1; off < 16; off <<= 1)
            acc[j] += __shfl_xor(acc[j], off);
    }
    if (ksub == 0) {
        int mbase = mhalf * 16;
        #pragma unroll
        for (int j = 0; j < 16; j++)
            C[(size_t)(mbase + j) * N + n] = acc[j];
    }
}

// mu/sigma GEMM with fused LN(Q): grid (128, 2, 2); y = split-K slab, z = w
// Slab layout in S: [z][by][32][1024]  (4 x 32768 floats)
__global__ void gemm_mu_sigma(const float* __restrict__ Q,
                              const float* __restrict__ W0,
                              const float* __restrict__ W1,
                              const float* __restrict__ ln_g,
                              const float* __restrict__ ln_b,
                              float* __restrict__ S) {
    const float* W = blockIdx.z ? W1 : W0;
    float* C = S + ((size_t)blockIdx.z * 2 + blockIdx.y) * 32768;
    gemm_fln_body(Q, W, C, nullptr, ln_g, ln_b,
                  1024, 1024, 512, 0, blockIdx.x, blockIdx.y);
}

// ffn1 GEMM with fused LN(x): grid (512); fused bias+silu epilogue
__global__ void gemm_ffn1(const float* __restrict__ X,
                          const float* __restrict__ W,
                          const float* __restrict__ ln_g,
                          const float* __restrict__ ln_b,
                          float* __restrict__ C,
                          const float* __restrict__ bias) {
    gemm_fln_body(X, W, C, bias, ln_g, ln_b,
                  4096, 1024, 1024, 1, blockIdx.x, 0);
}

// ffn2 GEMM: grid (128, 4); split-K plain stores into 4 slabs (no atomics)
__global__ void gemm_ffn2(const float* __restrict__ A,
                          const float* __restrict__ W,
                          float* __restrict__ S) {
    float* C = S + (size_t)blockIdx.y * 32768;
    gemm_body(A, W, C, 1024, 4096, 1024, blockIdx.x, blockIdx.y);
}

// ------------- Gaussian-kernel attention row sweep (the big one) ----------
// TWO rows per wave: 16 nt loads (8K+8V) in flight per lane, shuffle-reduce
// only — no LDS, no __syncthreads. Grid 4096 x 256 (4 waves = 8 rows/block).
__global__ void attn_kernel(const float* __restrict__ Kp,
                            const float* __restrict__ Vp,
                            const float* __restrict__ Qp,
                            const float* __restrict__ MS,   // mu slabs @0, sg slabs @65536
                            const float* __restrict__ mu_b,
                            const float* __restrict__ sg_b,
                            float* __restrict__ xo) {
    int t = threadIdx.x;
    int lane = t & 63, wid = t >> 6;
    int row0 = blockIdx.x * 8 + wid * 2;
    int row1 = row0 + 1;
    const f32x4* kp0 = (const f32x4*)(Kp + (size_t)row0 * D_DIM);
    const f32x4* vp0 = (const f32x4*)(Vp + (size_t)row0 * D_DIM);
    const f32x4* kp1 = (const f32x4*)(Kp + (size_t)row1 * D_DIM);
    const f32x4* vp1 = (const f32x4*)(Vp + (size_t)row1 * D_DIM);
    f32x4 ka[4], va[4], kb[4], vb[4];
    #pragma unroll
    for (int c = 0; c < 4; c++) ka[c] = __builtin_nontemporal_load(kp0 + c * 64 + lane);
    #pragma unroll
    for (int c = 0; c < 4; c++) kb[c] = __builtin_nontemporal_load(kp1 + c * 64 + lane);
    #pragma unroll
    for (int c = 0; c < 4; c++) va[c] = __builtin_nontemporal_load(vp0 + c * 64 + lane);
    #pragma unroll
    for (int c = 0; c < 4; c++) vb[c] = __builtin_nontemporal_load(vp1 + c * 64 + lane);
    int i0 = row0 & (N_TOK - 1), i1 = row1 & (N_TOK - 1);
    float mu0 = tanhf(MS[row0] + MS[row0 + 32768] + mu_b[i0]);
    float mu1 = tanhf(MS[row1] + MS[row1 + 32768] + mu_b[i1]);
    float sg0 = MS[row0 + 65536] + MS[row0 + 98304] + sg_b[i0];
    float sg1 = MS[row1 + 65536] + MS[row1 + 98304] + sg_b[i1];
    float c0 = -0.5f / (sg0 * sg0 + 1e-8f);
    float c1 = -0.5f / (sg1 * sg1 + 1e-8f);
    float acc0 = 0.f, acc1 = 0.f, d;
    #pragma unroll
    for (int c = 0; c < 4; c++) {
        d = ka[c].x - mu0; acc0 += __expf(c0 * d * d) * va[c].x;
        d = ka[c].y - mu0; acc0 += __expf(c0 * d * d) * va[c].y;
        d = ka[c].z - mu0; acc0 += __expf(c0 * d * d) * va[c].z;
        d = ka[c].w - mu0; acc0 += __expf(c0 * d * d) * va[c].w;
        d = kb[c].x - mu1; acc1 += __expf(c1 * d * d) * vb[c].x;
        d = kb[c].y - mu1; acc1 += __expf(c1 * d * d) * vb[c].y;
        d = kb[c].z - mu1; acc1 += __expf(c1 * d * d) * vb[c].z;
        d = kb[c].w - mu1; acc1 += __expf(c1 * d * d) * vb[c].w;
    }
    acc0 = wave_reduce(acc0);
    acc1 = wave_reduce(acc1);
    if (lane == 0) {
        xo[row0] = acc0 + Qp[row0];
        xo[row1] = acc1 + Qp[row1];
    }
}

// ------------- out = x + (s0+s1+s2+s3) + b2, f32 --------------------------
__global__ void final_kernel(const float* __restrict__ x,
                             const float* __restrict__ F2,  // 4 slabs
                             const float* __restrict__ b2,
                             float* __restrict__ out) {
    int idx = blockIdx.x * 256 + threadIdx.x;    // 32768 total
    float acc = (F2[idx] + F2[idx + 32768]) + (F2[idx + 65536] + F2[idx + 98304]);
    out[idx] = x[idx] + acc + b2[idx & (N_TOK - 1)];
}

extern "C" void kernel_launch(void* const* d_in, const int* in_sizes, int n_in,
                              void* d_out, int out_size, void* d_ws, size_t ws_size,
                              hipStream_t stream) {
    const float* Q       = (const float*)d_in[0];
    const float* Kp      = (const float*)d_in[1];
    const float* Vp      = (const float*)d_in[2];
    const float* mu_w    = (const float*)d_in[3];
    const float* mu_b    = (const float*)d_in[4];
    const float* sigma_w = (const float*)d_in[5];
    const float* sigma_b = (const float*)d_in[6];
    const float* w1      = (const float*)d_in[7];
    const float* b1      = (const float*)d_in[8];
    const float* w2      = (const float*)d_in[9];
    const float* b2      = (const float*)d_in[10];
    const float* ln_ff_g = (const float*)d_in[11];
    const float* ln_ff_b = (const float*)d_in[12];
    const float* ln_q_g  = (const float*)d_in[13];
    const float* ln_q_b  = (const float*)d_in[14];

    // Workspace (fp32); every buffer fully overwritten -> no memset/atomics.
    float* ms_sl  = (float*)d_ws;                  // 4 x 32768: mu(by0,by1), sg(by0,by1)
    float* f2_sl  = ms_sl  + 131072;               // 4 x 32768: ffn2 split-K slabs
    float* xbuf   = f2_sl  + 131072;               // 32768
    float* g      = xbuf   + 32768;                // 131072

    // 1) mu/sg split-K partials with LN(Q) folded into the GEMM
    gemm_mu_sigma<<<dim3(128, 2, 2), 256, 0, stream>>>(
        Q, mu_w, sigma_w, ln_q_g, ln_q_b, ms_sl);

    // 2) x = sum_d exp(-0.5(K-mu)^2/(sigma^2+1e-8)) * V + Q
    attn_kernel<<<4096, 256, 0, stream>>>(Kp, Vp, Q, ms_sl, mu_b, sigma_b, xbuf);

    // 3) g = silu(LN(x) @ w1^T + b1)   (LN + bias + silu all fused)
    gemm_ffn1<<<512, 256, 0, stream>>>(xbuf, w1, ln_ff_g, ln_ff_b, g, b1);

    // 4) f2 slabs = g @ w2^T partials ; out = x + (sum slabs) + b2
    gemm_ffn2<<<dim3(128, 4), 256, 0, stream>>>(g, w2, f2_sl);
    final_kernel<<<128, 256, 0, stream>>>(xbuf, f2_sl, b2, (float*)d_out);
}